// Round 2
// baseline (355.998 us; speedup 1.0000x reference)
//
#include <hip/hip_runtime.h>
#include <hip/hip_bf16.h>
#include <stdint.h>

// MHA forward: B=4, T=2048, D=1024, H=16, dk=64.  fp32 in/out, bf16 MFMA internally.
// R3: XOR bank-swizzle on all LDS tiles. R4: softmax de-VALU-ized.
// R6: fused QK->exp->PV per 16-key strip.
// R7: 64-key K/V tiles double-buffered in 32KiB, prefetch issued right after the
//     barrier; XCD-grouping swizzle -> attn FETCH 139->24.6MB (K/V L2-resident),
//     attn 112->104.7us.  Lesson: memory side solved; still no pipe >61% busy.
// R8: attn is issue-gap-bound (8 waves/CU can't cover the serial QK->exp->PV
//     dependency chain).  Widen block to 8 waves / 256 queries: same per-wave
//     inner loop, K/V shared by 8 waves -> staging halves, 2x512-thread blocks
//     co-resident -> 16 waves/CU.  T5 setprio around MFMA clusters (m191).
//     Bijective XCD-grouping swizzle added to gemm_qkv/gemm_out (A-panel reuse
//     within one XCD's L2, same mechanism that fixed attn's FETCH).

typedef __bf16 bf16x8 __attribute__((ext_vector_type(8)));
typedef short  v4s    __attribute__((ext_vector_type(4)));
typedef float  f32x4  __attribute__((ext_vector_type(4)));

#define LOG2E 1.44269504088896340736f

static __device__ __forceinline__ uint32_t f2bf(float x) {
  uint32_t u = __float_as_uint(x);
  u += 0x7fffu + ((u >> 16) & 1u);      // RNE
  return u >> 16;
}
#if __has_builtin(__builtin_amdgcn_cvt_pk_bf16_f32)
static __device__ __forceinline__ uint32_t pk2bf(float a, float b) {
  typedef __bf16 b2 __attribute__((ext_vector_type(2)));
  union { b2 v; uint32_t u; } x;
  x.v = __builtin_amdgcn_cvt_pk_bf16_f32(a, b);  // lo=a, hi=b
  return x.u;
}
#else
static __device__ __forceinline__ uint32_t pk2bf(float a, float b) {
  return f2bf(a) | (f2bf(b) << 16);
}
#endif
static __device__ __forceinline__ void gl2lds16(const void* g, void* l) {
  // async global->LDS, 16B/lane; LDS dest = wave-uniform base + lane*16
  __builtin_amdgcn_global_load_lds(
      (const __attribute__((address_space(1))) uint32_t*)g,
      (__attribute__((address_space(3))) uint32_t*)l, 16, 0, 0);
}

// ---------------- fp32 -> bf16 conversion of q/k/v (8 elems/thread) --------
__global__ void convert_inputs(const float* __restrict__ q, const float* __restrict__ k,
                               const float* __restrict__ v, uint16_t* __restrict__ qo,
                               uint16_t* __restrict__ ko, uint16_t* __restrict__ vo) {
  const float* src = blockIdx.y == 0 ? q : (blockIdx.y == 1 ? k : v);
  uint16_t*    dst = blockIdx.y == 0 ? qo : (blockIdx.y == 1 ? ko : vo);
  size_t idx = ((size_t)blockIdx.x * 256 + threadIdx.x) * 8;
  float4 a = *(const float4*)(src + idx);
  float4 b = *(const float4*)(src + idx + 4);
  uint4 o;
  o.x = pk2bf(a.x, a.y); o.y = pk2bf(a.z, a.w);
  o.z = pk2bf(b.x, b.y); o.w = pk2bf(b.z, b.w);
  *(uint4*)(dst + idx) = o;
}

// ---------------- W (K x N fp32) -> Wt (N x K bf16) ------------------------
__global__ void transpose_weights(const float* __restrict__ Wq, const float* __restrict__ Wk,
                                  const float* __restrict__ Wv, const float* __restrict__ Wo,
                                  uint16_t* __restrict__ out) {
  __shared__ float t[32][33];
  const float* W = blockIdx.z == 0 ? Wq : blockIdx.z == 1 ? Wk : blockIdx.z == 2 ? Wv : Wo;
  uint16_t* O = out + (size_t)blockIdx.z * 1048576;
  int tx = threadIdx.x & 31, ty = threadIdx.x >> 5;
  int r0 = blockIdx.y * 32, c0 = blockIdx.x * 32;
#pragma unroll
  for (int i = 0; i < 4; i++) t[ty + i * 8][tx] = W[(size_t)(r0 + ty + i * 8) * 1024 + c0 + tx];
  __syncthreads();
#pragma unroll
  for (int i = 0; i < 4; i++)
    O[(size_t)(c0 + ty + i * 8) * 1024 + r0 + tx] = (uint16_t)f2bf(t[tx][ty + i * 8]);
}

// ---------------- bf16 GEMM body: C = (A(MxK) * Bt(NxK)^T + bias) * oscale -
// Single-buffered 128x64 LDS tiles (8 chunks of 16B); XOR chunk swizzle by row&7.
// mode 0: fp32 natural   mode 1: bf16 natural   mode 2: bf16 V-transposed per head
static __device__ __forceinline__ void gemm_body(
    const uint16_t* __restrict__ A, const uint16_t* __restrict__ Bt,
    const float* __restrict__ bias, void* __restrict__ Cout,
    int N, int K, int mode, float oscale, int mBase, int nBase,
    uint16_t* __restrict__ lA, uint16_t* __restrict__ lB) {
  int tid = threadIdx.x, wave = tid >> 6, lane = tid & 63;
  int q = lane >> 4, c = lane & 15;
  int wrow = wave & 1, wcol = wave >> 1;
  f32x4 acc[4][4] = {};

  int swz = ((lane & 7) ^ (lane >> 3)) * 8;
  const uint16_t* gA = A + (size_t)(mBase + wave * 32 + (lane >> 3)) * K + swz;
  const uint16_t* gB = Bt + (size_t)(nBase + wave * 32 + (lane >> 3)) * K + swz;
  int cs = c & 7;

  for (int kt = 0; kt < K / 64; kt++) {
    __syncthreads();
    int k0 = kt * 64;
#pragma unroll
    for (int it = 0; it < 4; it++) {
      gl2lds16(gA + (size_t)(it * 8) * K + k0, &lA[(wave * 32 + it * 8) * 64]);
      gl2lds16(gB + (size_t)(it * 8) * K + k0, &lB[(wave * 32 + it * 8) * 64]);
    }
    __syncthreads();
#pragma unroll
    for (int kk = 0; kk < 2; kk++) {
      bf16x8 af[4], bfr[4];
#pragma unroll
      for (int i = 0; i < 4; i++)
        af[i] = *(const bf16x8*)&lA[(wrow * 64 + i * 16 + c) * 64 + ((kk * 4 + q) ^ cs) * 8];
#pragma unroll
      for (int j = 0; j < 4; j++)
        bfr[j] = *(const bf16x8*)&lB[(wcol * 64 + j * 16 + c) * 64 + ((kk * 4 + q) ^ cs) * 8];
#pragma unroll
      for (int i = 0; i < 4; i++)
#pragma unroll
        for (int j = 0; j < 4; j++)
          acc[i][j] = __builtin_amdgcn_mfma_f32_16x16x32_bf16(af[i], bfr[j], acc[i][j], 0, 0, 0);
    }
  }

  float bb[4];
#pragma unroll
  for (int j = 0; j < 4; j++) bb[j] = bias[nBase + wcol * 64 + j * 16 + c];

  if (mode == 0) {
    float* Co = (float*)Cout;
#pragma unroll
    for (int i = 0; i < 4; i++)
#pragma unroll
      for (int j = 0; j < 4; j++) {
        int row = mBase + wrow * 64 + i * 16 + q * 4;
        int col = nBase + wcol * 64 + j * 16 + c;
#pragma unroll
        for (int r = 0; r < 4; r++) Co[(size_t)(row + r) * N + col] = acc[i][j][r] + bb[j];
      }
  } else if (mode == 1) {
    uint16_t* Co = (uint16_t*)Cout;
#pragma unroll
    for (int i = 0; i < 4; i++)
#pragma unroll
      for (int j = 0; j < 4; j++) {
        int row = mBase + wrow * 64 + i * 16 + q * 4;
        int col = nBase + wcol * 64 + j * 16 + c;
#pragma unroll
        for (int r = 0; r < 4; r++)
          Co[(size_t)(row + r) * N + col] = (uint16_t)f2bf((acc[i][j][r] + bb[j]) * oscale);
      }
  } else {  // V: write Vt[(b*16+h)*64+d][t]
    uint16_t* Co = (uint16_t*)Cout;
#pragma unroll
    for (int i = 0; i < 4; i++)
#pragma unroll
      for (int j = 0; j < 4; j++) {
        int n = nBase + wcol * 64 + j * 16 + c;
        int h = n >> 6, d = n & 63;
        int m = mBase + wrow * 64 + i * 16 + q * 4;
        int b = m >> 11, t = m & 2047;
        uint32_t lo = pk2bf(acc[i][j][0] + bb[j], acc[i][j][1] + bb[j]);
        uint32_t hi = pk2bf(acc[i][j][2] + bb[j], acc[i][j][3] + bb[j]);
        *(uint2*)(Co + (size_t)((b * 16 + h) * 64 + d) * 2048 + t) = make_uint2(lo, hi);
      }
  }
}

// Q/K/V projections batched: grid (8, 64, 3).  XCD-grouping swizzle: XCD k owns
// A-row-panels y in [8k,8k+8) for all (x,z), so each 256KB A panel is fetched by
// one XCD's L2 instead of 8.
__global__ __launch_bounds__(256, 2)
void gemm_qkv(const uint16_t* __restrict__ qb, const uint16_t* __restrict__ kb,
              const uint16_t* __restrict__ vb, const uint16_t* __restrict__ Wtq,
              const uint16_t* __restrict__ Wtk, const uint16_t* __restrict__ Wtv,
              const float* __restrict__ bq, const float* __restrict__ bk,
              const float* __restrict__ bv, uint16_t* __restrict__ Qp,
              uint16_t* __restrict__ Kp, uint16_t* __restrict__ Vt, float cs) {
  __shared__ uint16_t lA[8192], lB[8192];
  int id = blockIdx.x + (blockIdx.y << 3) + (blockIdx.z << 9);  // 0..1535
  int xcd = id & 7, j = id >> 3;                                // j: 0..191
  int by = xcd * 8 + (j & 7);
  int bx = (j >> 3) & 7;
  int z  = j >> 6;
  const uint16_t* A  = z == 0 ? qb : (z == 1 ? kb : vb);
  const uint16_t* Bt = z == 0 ? Wtq : (z == 1 ? Wtk : Wtv);
  const float* bias  = z == 0 ? bq : (z == 1 ? bk : bv);
  void* C            = z == 0 ? (void*)Qp : (z == 1 ? (void*)Kp : (void*)Vt);
  int mode   = z == 2 ? 2 : 1;
  float os   = z == 0 ? cs : 1.0f;
  gemm_body(A, Bt, bias, C, 1024, 1024, mode, os, by * 128, bx * 128, lA, lB);
}

__global__ __launch_bounds__(256, 2)
void gemm_out(const uint16_t* __restrict__ A, const uint16_t* __restrict__ Bt,
              const float* __restrict__ bias, float* __restrict__ C) {
  __shared__ uint16_t lA[8192], lB[8192];
  int id = blockIdx.x + (blockIdx.y << 3);  // 0..511
  int xcd = id & 7, j = id >> 3;            // j: 0..63
  int by = xcd * 8 + (j & 7);
  int bx = j >> 3;
  gemm_body(A, Bt, bias, C, 1024, 1024, 0, 1.0f, by * 128, bx * 128, lA, lB);
}

// ---------------- flash attention ------------------------------------------
// grid (8, 64), 512 threads (8 waves).  After the XCD swizzle: x = 256-query
// tile, y = b*16+h; XCD k owns bh in [8k,8k+8) (its K+V = 4MB = its L2).
// S^T = K*Q^T orientation: softmax key axis = MFMA rows; P feeds PV
// (16x16x16 mfma) straight from regs.  Q pre-scaled by 0.125*log2e ->
// p = exp2(s), no online max (shift-safe, softmax renormalizes).
// 64-key K/V tiles double-buffered in 32KiB:
//   lds[    0.. 4096) = K buf0    lds[ 4096.. 8192) = K buf1
//   lds[ 8192..12288) = V buf0    lds[12288..16384) = V buf1
// (whole 16384-element LDS holds the 256x64 Q tile during the prologue).
// Per kt: barrier (drains prefetch kt) -> issue stage(kt+1 -> other buf) ->
// fused QK/exp/PV on cur buf.  8 waves share each K/V tile -> staging per
// query is half of R7; 2 blocks/CU -> 16 waves/CU of TLP.
__global__ __launch_bounds__(512, 4)
void attn(const uint16_t* __restrict__ Qp, const uint16_t* __restrict__ Kp,
          const uint16_t* __restrict__ Vt, uint16_t* __restrict__ Ob) {
  __shared__ uint16_t lds[16384];
  int tid = threadIdx.x, wave = tid >> 6, lane = tid & 63;
  int q = lane >> 4, c = lane & 15;
  int cs = c & 7;

  int id = blockIdx.y * 8 + blockIdx.x;  // 0..511
  int wk = (id & 7) * 64 + (id >> 3);    // bijective XCD grouping
  int qt = wk & 7, bh = wk >> 3;
  int b = bh >> 4, h = bh & 15;
  int qbase = qt * 256;
  int swz = ((lane & 7) ^ (lane >> 3)) * 8;

  {  // stage Q tile (256 x 64) into the whole LDS, swizzled
    const uint16_t* gQ =
        Qp + (size_t)(b * 2048 + qbase + wave * 32 + (lane >> 3)) * 1024 + h * 64 + swz;
#pragma unroll
    for (int it = 0; it < 4; it++)
      gl2lds16(gQ + (size_t)(it * 8) * 1024, &lds[(wave * 32 + it * 8) * 64]);
  }
  __syncthreads();
  bf16x8 qf[2][2];
#pragma unroll
  for (int it = 0; it < 2; it++)
#pragma unroll
    for (int kk = 0; kk < 2; kk++)
      qf[it][kk] =
          *(const bf16x8*)&lds[(wave * 32 + it * 16 + c) * 64 + ((kk * 4 + q) ^ cs) * 8];
  __syncthreads();  // all waves' qf reads done before K tile 0 overwrites Q

  f32x4 o[4][2] = {};
  float rs0 = 0.f, rs1 = 0.f;

  // K tile kt: 64 keys x 64 d; each of 8 waves stages 8 key-rows (1 gl2lds).
  // V tile kt: 64 d-rows x 64 keys; each wave stages 8 d-rows (1 gl2lds).
  // Both use the row&7 == lane>>3 XOR chunk swizzle (read side uses cs=c&7).
  const uint16_t* gK0 =
      Kp + (size_t)(b * 2048 + wave * 8 + (lane >> 3)) * 1024 + h * 64 + swz;
  const uint16_t* gV0 = Vt + (size_t)(bh * 64 + wave * 8 + (lane >> 3)) * 2048 + swz;

  // prologue: stage tile 0 into buf 0
  gl2lds16(gK0, &lds[(wave * 8) * 64]);
  gl2lds16(gV0, &lds[8192 + (wave * 8) * 64]);

  for (int kt = 0; kt < 32; kt++) {
    int cur = kt & 1;
    __syncthreads();  // vmcnt(0) drain: tile kt now resident in buf[cur]

    if (kt < 31) {  // prefetch tile kt+1 into the other buffer
      int nb = (cur ^ 1) * 4096;
      gl2lds16(gK0 + (size_t)(kt + 1) * 64 * 1024, &lds[nb + (wave * 8) * 64]);
      gl2lds16(gV0 + (size_t)(kt + 1) * 64, &lds[8192 + nb + (wave * 8) * 64]);
    }

    const uint16_t* sKc = &lds[cur * 4096];
    const uint16_t* sVc = &lds[8192 + cur * 4096];

    // fused: per 16-key strip, QK (MFMA) -> exp/pack (VALU) -> PV (MFMA)
#pragma unroll
    for (int jt = 0; jt < 4; jt++) {
      bf16x8 a0 = *(const bf16x8*)&sKc[(jt * 16 + c) * 64 + (q ^ cs) * 8];
      bf16x8 a1 = *(const bf16x8*)&sKc[(jt * 16 + c) * 64 + ((4 + q) ^ cs) * 8];
      __builtin_amdgcn_s_setprio(1);
      f32x4 s0 = __builtin_amdgcn_mfma_f32_16x16x32_bf16(a0, qf[0][0],
                                                         (f32x4){0.f, 0.f, 0.f, 0.f}, 0, 0, 0);
      s0 = __builtin_amdgcn_mfma_f32_16x16x32_bf16(a1, qf[0][1], s0, 0, 0, 0);
      f32x4 s1 = __builtin_amdgcn_mfma_f32_16x16x32_bf16(a0, qf[1][0],
                                                         (f32x4){0.f, 0.f, 0.f, 0.f}, 0, 0, 0);
      s1 = __builtin_amdgcn_mfma_f32_16x16x32_bf16(a1, qf[1][1], s1, 0, 0, 0);
      __builtin_amdgcn_s_setprio(0);

      float p00 = __builtin_amdgcn_exp2f(s0[0]), p01 = __builtin_amdgcn_exp2f(s0[1]);
      float p02 = __builtin_amdgcn_exp2f(s0[2]), p03 = __builtin_amdgcn_exp2f(s0[3]);
      float p10 = __builtin_amdgcn_exp2f(s1[0]), p11 = __builtin_amdgcn_exp2f(s1[1]);
      float p12 = __builtin_amdgcn_exp2f(s1[2]), p13 = __builtin_amdgcn_exp2f(s1[3]);
      rs0 += (p00 + p01) + (p02 + p03);
      rs1 += (p10 + p11) + (p12 + p13);
      union { uint32_t u[2]; v4s s4; } pb0, pb1;
      pb0.u[0] = pk2bf(p00, p01); pb0.u[1] = pk2bf(p02, p03);
      pb1.u[0] = pk2bf(p10, p11); pb1.u[1] = pk2bf(p12, p13);

      __builtin_amdgcn_s_setprio(1);
#pragma unroll
      for (int mt = 0; mt < 4; mt++) {
        v4s a = *(const v4s*)&sVc[(mt * 16 + c) * 64 + (((jt * 2 + (q >> 1)) ^ cs) * 8) +
                                  (q & 1) * 4];
        o[mt][0] = __builtin_amdgcn_mfma_f32_16x16x16bf16_1k(a, pb0.s4, o[mt][0], 0, 0, 0);
        o[mt][1] = __builtin_amdgcn_mfma_f32_16x16x16bf16_1k(a, pb1.s4, o[mt][1], 0, 0, 0);
      }
      __builtin_amdgcn_s_setprio(0);
    }
  }

  // deferred l reduction (valid: no online-max rescaling, l is a plain sum)
  rs0 += __shfl_xor(rs0, 16); rs0 += __shfl_xor(rs0, 32);
  rs1 += __shfl_xor(rs1, 16); rs1 += __shfl_xor(rs1, 32);
  float l[2] = {rs0, rs1};

  // epilogue: attn[t][h*64+d] bf16, 4 consecutive d per 8B store
#pragma unroll
  for (int it = 0; it < 2; it++) {
    float inv = 1.0f / l[it];
    size_t trow = (size_t)(b * 2048 + qbase + wave * 32 + it * 16 + c) * 1024 + h * 64;
#pragma unroll
    for (int mt = 0; mt < 4; mt++) {
      uint32_t lo = pk2bf(o[mt][it][0] * inv, o[mt][it][1] * inv);
      uint32_t hi = pk2bf(o[mt][it][2] * inv, o[mt][it][3] * inv);
      *(uint2*)(Ob + trow + mt * 16 + q * 4) = make_uint2(lo, hi);
    }
  }
}

extern "C" void kernel_launch(void* const* d_in, const int* in_sizes, int n_in,
                              void* d_out, int out_size, void* d_ws, size_t ws_size,
                              hipStream_t stream) {
  (void)in_sizes; (void)n_in; (void)out_size; (void)ws_size;
  const float* query = (const float*)d_in[0];
  const float* key_  = (const float*)d_in[1];
  const float* value = (const float*)d_in[2];
  const float* Wq = (const float*)d_in[3]; const float* bq = (const float*)d_in[4];
  const float* Wk = (const float*)d_in[5]; const float* bk = (const float*)d_in[6];
  const float* Wv = (const float*)d_in[7]; const float* bv = (const float*)d_in[8];
  const float* Wo = (const float*)d_in[9]; const float* bo = (const float*)d_in[10];

  const size_t SZ = (size_t)8192 * 1024;  // elements per (B*T, D) bf16 tensor
  uint16_t* buf0 = (uint16_t*)d_ws;       // qb
  uint16_t* buf1 = buf0 + SZ;             // kb
  uint16_t* buf2 = buf1 + SZ;             // vb -> later attn-out
  uint16_t* buf3 = buf2 + SZ;             // Qp
  uint16_t* wts  = buf3 + SZ;             // 4 x 1M bf16 transposed weights
  uint16_t* Wtq = wts;
  uint16_t* Wtk = wts + 1048576;
  uint16_t* Wtv = wts + 2097152;
  uint16_t* Wto = wts + 3145728;
  uint16_t* Kp  = wts + 4194304;
  uint16_t* Vt  = Kp + SZ;

  const float Cs = 0.125f * LOG2E;  // folded into Q projection

  convert_inputs<<<dim3(4096, 3), 256, 0, stream>>>(query, key_, value, buf0, buf1, buf2);
  transpose_weights<<<dim3(32, 32, 4), 256, 0, stream>>>(Wq, Wk, Wv, Wo, wts);
  gemm_qkv<<<dim3(8, 64, 3), 256, 0, stream>>>(buf0, buf1, buf2, Wtq, Wtk, Wtv,
                                               bq, bk, bv, buf3, Kp, Vt, Cs);
  attn<<<dim3(8, 64), 512, 0, stream>>>(buf3, Kp, Vt, buf2);
  gemm_out<<<dim3(8, 64), 256, 0, stream>>>(buf2, Wto, bo, (float*)d_out);
}

// Round 3
// 348.233 us; speedup vs baseline: 1.0223x; 1.0223x over previous
//
#include <hip/hip_runtime.h>
#include <hip/hip_bf16.h>
#include <stdint.h>

// MHA forward: B=4, T=2048, D=1024, H=16, dk=64.  fp32 in/out, bf16 MFMA internally.
// R3: XOR bank-swizzle on all LDS tiles. R4: softmax de-VALU-ized.
// R6: fused QK->exp->PV per 16-key strip.
// R7: 64-key K/V dbuf tiles, prefetch-after-barrier; XCD-grouping swizzle ->
//     attn FETCH 139->24.6MB, 104.7us.
// R8 lesson: widening to 8 barrier-locked waves REGRESSED attn (114.6us, both
//     pipes dropped) -> lockstep waves contend per-phase; setprio hurts in
//     lockstep (m190).  GEMM XCD swizzle saved ~9us -> kept.
// R9: revert attn to R7 shape (4 waves/128q), no setprio.  Two additions:
//     (a) T15 2-deep strip pipeline: issue strip j+1's QK MFMAs before strip
//         j's exp/PV, hiding MFMA latency under VALU within one wave;
//     (b) l-by-MFMA: softmax denominator accumulated via ones-A MFMA into a
//         dedicated accumulator (all rows identical -> l = lacc[0], no adds,
//         no shuffles) -> moves 8 VALU adds/strip to the idle MFMA pipe.

typedef __bf16 bf16x8 __attribute__((ext_vector_type(8)));
typedef short  v4s    __attribute__((ext_vector_type(4)));
typedef float  f32x4  __attribute__((ext_vector_type(4)));

#define LOG2E 1.44269504088896340736f

static __device__ __forceinline__ uint32_t f2bf(float x) {
  uint32_t u = __float_as_uint(x);
  u += 0x7fffu + ((u >> 16) & 1u);      // RNE
  return u >> 16;
}
#if __has_builtin(__builtin_amdgcn_cvt_pk_bf16_f32)
static __device__ __forceinline__ uint32_t pk2bf(float a, float b) {
  typedef __bf16 b2 __attribute__((ext_vector_type(2)));
  union { b2 v; uint32_t u; } x;
  x.v = __builtin_amdgcn_cvt_pk_bf16_f32(a, b);  // lo=a, hi=b
  return x.u;
}
#else
static __device__ __forceinline__ uint32_t pk2bf(float a, float b) {
  return f2bf(a) | (f2bf(b) << 16);
}
#endif
static __device__ __forceinline__ void gl2lds16(const void* g, void* l) {
  // async global->LDS, 16B/lane; LDS dest = wave-uniform base + lane*16
  __builtin_amdgcn_global_load_lds(
      (const __attribute__((address_space(1))) uint32_t*)g,
      (__attribute__((address_space(3))) uint32_t*)l, 16, 0, 0);
}

// ---------------- fp32 -> bf16 conversion of q/k/v (8 elems/thread) --------
__global__ void convert_inputs(const float* __restrict__ q, const float* __restrict__ k,
                               const float* __restrict__ v, uint16_t* __restrict__ qo,
                               uint16_t* __restrict__ ko, uint16_t* __restrict__ vo) {
  const float* src = blockIdx.y == 0 ? q : (blockIdx.y == 1 ? k : v);
  uint16_t*    dst = blockIdx.y == 0 ? qo : (blockIdx.y == 1 ? ko : vo);
  size_t idx = ((size_t)blockIdx.x * 256 + threadIdx.x) * 8;
  float4 a = *(const float4*)(src + idx);
  float4 b = *(const float4*)(src + idx + 4);
  uint4 o;
  o.x = pk2bf(a.x, a.y); o.y = pk2bf(a.z, a.w);
  o.z = pk2bf(b.x, b.y); o.w = pk2bf(b.z, b.w);
  *(uint4*)(dst + idx) = o;
}

// ---------------- W (K x N fp32) -> Wt (N x K bf16) ------------------------
__global__ void transpose_weights(const float* __restrict__ Wq, const float* __restrict__ Wk,
                                  const float* __restrict__ Wv, const float* __restrict__ Wo,
                                  uint16_t* __restrict__ out) {
  __shared__ float t[32][33];
  const float* W = blockIdx.z == 0 ? Wq : blockIdx.z == 1 ? Wk : blockIdx.z == 2 ? Wv : Wo;
  uint16_t* O = out + (size_t)blockIdx.z * 1048576;
  int tx = threadIdx.x & 31, ty = threadIdx.x >> 5;
  int r0 = blockIdx.y * 32, c0 = blockIdx.x * 32;
#pragma unroll
  for (int i = 0; i < 4; i++) t[ty + i * 8][tx] = W[(size_t)(r0 + ty + i * 8) * 1024 + c0 + tx];
  __syncthreads();
#pragma unroll
  for (int i = 0; i < 4; i++)
    O[(size_t)(c0 + ty + i * 8) * 1024 + r0 + tx] = (uint16_t)f2bf(t[tx][ty + i * 8]);
}

// ---------------- bf16 GEMM body: C = (A(MxK) * Bt(NxK)^T + bias) * oscale -
// Single-buffered 128x64 LDS tiles (8 chunks of 16B); XOR chunk swizzle by row&7.
// mode 0: fp32 natural   mode 1: bf16 natural   mode 2: bf16 V-transposed per head
static __device__ __forceinline__ void gemm_body(
    const uint16_t* __restrict__ A, const uint16_t* __restrict__ Bt,
    const float* __restrict__ bias, void* __restrict__ Cout,
    int N, int K, int mode, float oscale, int mBase, int nBase,
    uint16_t* __restrict__ lA, uint16_t* __restrict__ lB) {
  int tid = threadIdx.x, wave = tid >> 6, lane = tid & 63;
  int q = lane >> 4, c = lane & 15;
  int wrow = wave & 1, wcol = wave >> 1;
  f32x4 acc[4][4] = {};

  int swz = ((lane & 7) ^ (lane >> 3)) * 8;
  const uint16_t* gA = A + (size_t)(mBase + wave * 32 + (lane >> 3)) * K + swz;
  const uint16_t* gB = Bt + (size_t)(nBase + wave * 32 + (lane >> 3)) * K + swz;
  int cs = c & 7;

  for (int kt = 0; kt < K / 64; kt++) {
    __syncthreads();
    int k0 = kt * 64;
#pragma unroll
    for (int it = 0; it < 4; it++) {
      gl2lds16(gA + (size_t)(it * 8) * K + k0, &lA[(wave * 32 + it * 8) * 64]);
      gl2lds16(gB + (size_t)(it * 8) * K + k0, &lB[(wave * 32 + it * 8) * 64]);
    }
    __syncthreads();
#pragma unroll
    for (int kk = 0; kk < 2; kk++) {
      bf16x8 af[4], bfr[4];
#pragma unroll
      for (int i = 0; i < 4; i++)
        af[i] = *(const bf16x8*)&lA[(wrow * 64 + i * 16 + c) * 64 + ((kk * 4 + q) ^ cs) * 8];
#pragma unroll
      for (int j = 0; j < 4; j++)
        bfr[j] = *(const bf16x8*)&lB[(wcol * 64 + j * 16 + c) * 64 + ((kk * 4 + q) ^ cs) * 8];
#pragma unroll
      for (int i = 0; i < 4; i++)
#pragma unroll
        for (int j = 0; j < 4; j++)
          acc[i][j] = __builtin_amdgcn_mfma_f32_16x16x32_bf16(af[i], bfr[j], acc[i][j], 0, 0, 0);
    }
  }

  float bb[4];
#pragma unroll
  for (int j = 0; j < 4; j++) bb[j] = bias[nBase + wcol * 64 + j * 16 + c];

  if (mode == 0) {
    float* Co = (float*)Cout;
#pragma unroll
    for (int i = 0; i < 4; i++)
#pragma unroll
      for (int j = 0; j < 4; j++) {
        int row = mBase + wrow * 64 + i * 16 + q * 4;
        int col = nBase + wcol * 64 + j * 16 + c;
#pragma unroll
        for (int r = 0; r < 4; r++) Co[(size_t)(row + r) * N + col] = acc[i][j][r] + bb[j];
      }
  } else if (mode == 1) {
    uint16_t* Co = (uint16_t*)Cout;
#pragma unroll
    for (int i = 0; i < 4; i++)
#pragma unroll
      for (int j = 0; j < 4; j++) {
        int row = mBase + wrow * 64 + i * 16 + q * 4;
        int col = nBase + wcol * 64 + j * 16 + c;
#pragma unroll
        for (int r = 0; r < 4; r++)
          Co[(size_t)(row + r) * N + col] = (uint16_t)f2bf((acc[i][j][r] + bb[j]) * oscale);
      }
  } else {  // V: write Vt[(b*16+h)*64+d][t]
    uint16_t* Co = (uint16_t*)Cout;
#pragma unroll
    for (int i = 0; i < 4; i++)
#pragma unroll
      for (int j = 0; j < 4; j++) {
        int n = nBase + wcol * 64 + j * 16 + c;
        int h = n >> 6, d = n & 63;
        int m = mBase + wrow * 64 + i * 16 + q * 4;
        int b = m >> 11, t = m & 2047;
        uint32_t lo = pk2bf(acc[i][j][0] + bb[j], acc[i][j][1] + bb[j]);
        uint32_t hi = pk2bf(acc[i][j][2] + bb[j], acc[i][j][3] + bb[j]);
        *(uint2*)(Co + (size_t)((b * 16 + h) * 64 + d) * 2048 + t) = make_uint2(lo, hi);
      }
  }
}

// Q/K/V projections batched: grid (8, 64, 3).  XCD-grouping swizzle: XCD k owns
// A-row-panels y in [8k,8k+8) for all (x,z), so each 256KB A panel is fetched by
// one XCD's L2 instead of 8.
__global__ __launch_bounds__(256, 2)
void gemm_qkv(const uint16_t* __restrict__ qb, const uint16_t* __restrict__ kb,
              const uint16_t* __restrict__ vb, const uint16_t* __restrict__ Wtq,
              const uint16_t* __restrict__ Wtk, const uint16_t* __restrict__ Wtv,
              const float* __restrict__ bq, const float* __restrict__ bk,
              const float* __restrict__ bv, uint16_t* __restrict__ Qp,
              uint16_t* __restrict__ Kp, uint16_t* __restrict__ Vt, float cs) {
  __shared__ uint16_t lA[8192], lB[8192];
  int id = blockIdx.x + (blockIdx.y << 3) + (blockIdx.z << 9);  // 0..1535
  int xcd = id & 7, j = id >> 3;                                // j: 0..191
  int by = xcd * 8 + (j & 7);
  int bx = (j >> 3) & 7;
  int z  = j >> 6;
  const uint16_t* A  = z == 0 ? qb : (z == 1 ? kb : vb);
  const uint16_t* Bt = z == 0 ? Wtq : (z == 1 ? Wtk : Wtv);
  const float* bias  = z == 0 ? bq : (z == 1 ? bk : bv);
  void* C            = z == 0 ? (void*)Qp : (z == 1 ? (void*)Kp : (void*)Vt);
  int mode   = z == 2 ? 2 : 1;
  float os   = z == 0 ? cs : 1.0f;
  gemm_body(A, Bt, bias, C, 1024, 1024, mode, os, by * 128, bx * 128, lA, lB);
}

__global__ __launch_bounds__(256, 2)
void gemm_out(const uint16_t* __restrict__ A, const uint16_t* __restrict__ Bt,
              const float* __restrict__ bias, float* __restrict__ C) {
  __shared__ uint16_t lA[8192], lB[8192];
  int id = blockIdx.x + (blockIdx.y << 3);  // 0..511
  int xcd = id & 7, j = id >> 3;            // j: 0..63
  int by = xcd * 8 + (j & 7);
  int bx = j >> 3;
  gemm_body(A, Bt, bias, C, 1024, 1024, 0, 1.0f, by * 128, bx * 128, lA, lB);
}

// ---------------- flash attention ------------------------------------------
// grid (16, 64), 256 threads (4 waves).  After the XCD swizzle: x = 128-query
// tile, y = b*16+h; XCD k owns bh in [8k,8k+8) (its K+V = 4MB = its L2).
// S^T = K*Q^T orientation; Q pre-scaled by 0.125*log2e -> p = exp2(s), no
// online max (shift-safe, softmax renormalizes).
// 64-key K/V tiles double-buffered in 32KiB:
//   lds[    0.. 4096) = K buf0    lds[ 4096.. 8192) = K buf1
//   lds[ 8192..12288) = V buf0    lds[12288..16384) = V buf1
// Per kt: barrier (drains prefetch kt) -> issue stage(kt+1 -> other buf) ->
// strips.  R9: 2-deep strip pipeline (QK of strip j+1 issued before exp/PV of
// strip j) + softmax denominator via ones-A MFMA (lacc; all output rows equal
// the column sum, so l = lacc[0] -- no VALU adds, no shuffles).
__global__ __launch_bounds__(256, 2)
void attn(const uint16_t* __restrict__ Qp, const uint16_t* __restrict__ Kp,
          const uint16_t* __restrict__ Vt, uint16_t* __restrict__ Ob) {
  __shared__ uint16_t lds[16384];
  int tid = threadIdx.x, wave = tid >> 6, lane = tid & 63;
  int q = lane >> 4, c = lane & 15;
  int cs = c & 7;

  int id = blockIdx.y * 16 + blockIdx.x;     // 0..1023
  int wk = (id & 7) * 128 + (id >> 3);       // bijective XCD grouping
  int qt = wk & 15, bh = wk >> 4;
  int b = bh >> 4, h = bh & 15;
  int qbase = qt * 128;
  int swz = ((lane & 7) ^ (lane >> 3)) * 8;

  {  // stage Q tile (128 x 64) into lds[0..8192), swizzled
    const uint16_t* gQ =
        Qp + (size_t)(b * 2048 + qbase + wave * 32 + (lane >> 3)) * 1024 + h * 64 + swz;
#pragma unroll
    for (int it = 0; it < 4; it++)
      gl2lds16(gQ + (size_t)(it * 8) * 1024, &lds[(wave * 32 + it * 8) * 64]);
  }
  __syncthreads();
  bf16x8 qf[2][2];
#pragma unroll
  for (int it = 0; it < 2; it++)
#pragma unroll
    for (int kk = 0; kk < 2; kk++)
      qf[it][kk] =
          *(const bf16x8*)&lds[(wave * 32 + it * 16 + c) * 64 + ((kk * 4 + q) ^ cs) * 8];
  __syncthreads();  // all waves' qf reads done before K tile 0 overwrites Q

  f32x4 o[4][2] = {};
  f32x4 lacc[2] = {};
  const v4s vone = {(short)0x3F80, (short)0x3F80, (short)0x3F80, (short)0x3F80};  // bf16 1.0

  const uint16_t* gK0 =
      Kp + (size_t)(b * 2048 + wave * 16 + (lane >> 3)) * 1024 + h * 64 + swz;
  const uint16_t* gV0 = Vt + (size_t)(bh * 64 + wave * 16 + (lane >> 3)) * 2048 + swz;

  // prologue: stage tile 0 into buf 0
#pragma unroll
  for (int it = 0; it < 2; it++) {
    gl2lds16(gK0 + (size_t)(it * 8) * 1024, &lds[(wave * 16 + it * 8) * 64]);
    gl2lds16(gV0 + (size_t)(it * 8) * 2048, &lds[8192 + (wave * 16 + it * 8) * 64]);
  }

  for (int kt = 0; kt < 32; kt++) {
    int cur = kt & 1;
    __syncthreads();  // vmcnt(0) drain: tile kt now resident in buf[cur]

    if (kt < 31) {  // prefetch tile kt+1 into the other buffer
      int nb = (cur ^ 1) * 4096;
#pragma unroll
      for (int it = 0; it < 2; it++) {
        gl2lds16(gK0 + (size_t)((kt + 1) * 64 + it * 8) * 1024,
                 &lds[nb + (wave * 16 + it * 8) * 64]);
        gl2lds16(gV0 + (size_t)(it * 8) * 2048 + (kt + 1) * 64,
                 &lds[8192 + nb + (wave * 16 + it * 8) * 64]);
      }
    }

    const uint16_t* sKc = &lds[cur * 4096];
    const uint16_t* sVc = &lds[8192 + cur * 4096];

    // 2-deep strip pipeline: QK(j+1) in flight while exp/PV(j) runs.
    f32x4 s0, s1, n0, n1;
    {
      bf16x8 a0 = *(const bf16x8*)&sKc[(c)*64 + (q ^ cs) * 8];
      bf16x8 a1 = *(const bf16x8*)&sKc[(c)*64 + ((4 + q) ^ cs) * 8];
      s0 = __builtin_amdgcn_mfma_f32_16x16x32_bf16(a0, qf[0][0],
                                                   (f32x4){0.f, 0.f, 0.f, 0.f}, 0, 0, 0);
      s0 = __builtin_amdgcn_mfma_f32_16x16x32_bf16(a1, qf[0][1], s0, 0, 0, 0);
      s1 = __builtin_amdgcn_mfma_f32_16x16x32_bf16(a0, qf[1][0],
                                                   (f32x4){0.f, 0.f, 0.f, 0.f}, 0, 0, 0);
      s1 = __builtin_amdgcn_mfma_f32_16x16x32_bf16(a1, qf[1][1], s1, 0, 0, 0);
    }
#pragma unroll
    for (int jt = 0; jt < 4; jt++) {
      if (jt < 3) {
        bf16x8 a0 = *(const bf16x8*)&sKc[((jt + 1) * 16 + c) * 64 + (q ^ cs) * 8];
        bf16x8 a1 = *(const bf16x8*)&sKc[((jt + 1) * 16 + c) * 64 + ((4 + q) ^ cs) * 8];
        n0 = __builtin_amdgcn_mfma_f32_16x16x32_bf16(a0, qf[0][0],
                                                     (f32x4){0.f, 0.f, 0.f, 0.f}, 0, 0, 0);
        n0 = __builtin_amdgcn_mfma_f32_16x16x32_bf16(a1, qf[0][1], n0, 0, 0, 0);
        n1 = __builtin_amdgcn_mfma_f32_16x16x32_bf16(a0, qf[1][0],
                                                     (f32x4){0.f, 0.f, 0.f, 0.f}, 0, 0, 0);
        n1 = __builtin_amdgcn_mfma_f32_16x16x32_bf16(a1, qf[1][1], n1, 0, 0, 0);
      }

      float p00 = __builtin_amdgcn_exp2f(s0[0]), p01 = __builtin_amdgcn_exp2f(s0[1]);
      float p02 = __builtin_amdgcn_exp2f(s0[2]), p03 = __builtin_amdgcn_exp2f(s0[3]);
      float p10 = __builtin_amdgcn_exp2f(s1[0]), p11 = __builtin_amdgcn_exp2f(s1[1]);
      float p12 = __builtin_amdgcn_exp2f(s1[2]), p13 = __builtin_amdgcn_exp2f(s1[3]);
      union { uint32_t u[2]; v4s s4; } pb0, pb1;
      pb0.u[0] = pk2bf(p00, p01); pb0.u[1] = pk2bf(p02, p03);
      pb1.u[0] = pk2bf(p10, p11); pb1.u[1] = pk2bf(p12, p13);

      // softmax denominator on the MFMA pipe: rows of ones*P = column sums
      lacc[0] = __builtin_amdgcn_mfma_f32_16x16x16bf16_1k(vone, pb0.s4, lacc[0], 0, 0, 0);
      lacc[1] = __builtin_amdgcn_mfma_f32_16x16x16bf16_1k(vone, pb1.s4, lacc[1], 0, 0, 0);

#pragma unroll
      for (int mt = 0; mt < 4; mt++) {
        v4s a = *(const v4s*)&sVc[(mt * 16 + c) * 64 + (((jt * 2 + (q >> 1)) ^ cs) * 8) +
                                  (q & 1) * 4];
        o[mt][0] = __builtin_amdgcn_mfma_f32_16x16x16bf16_1k(a, pb0.s4, o[mt][0], 0, 0, 0);
        o[mt][1] = __builtin_amdgcn_mfma_f32_16x16x16bf16_1k(a, pb1.s4, o[mt][1], 0, 0, 0);
      }
      if (jt < 3) { s0 = n0; s1 = n1; }
    }
  }

  // l = column sums (all rows/regs of lacc identical) -- no shuffles needed
  float l[2] = {lacc[0][0], lacc[1][0]};

  // epilogue: attn[t][h*64+d] bf16, 4 consecutive d per 8B store
#pragma unroll
  for (int it = 0; it < 2; it++) {
    float inv = 1.0f / l[it];
    size_t trow = (size_t)(b * 2048 + qbase + wave * 32 + it * 16 + c) * 1024 + h * 64;
#pragma unroll
    for (int mt = 0; mt < 4; mt++) {
      uint32_t lo = pk2bf(o[mt][it][0] * inv, o[mt][it][1] * inv);
      uint32_t hi = pk2bf(o[mt][it][2] * inv, o[mt][it][3] * inv);
      *(uint2*)(Ob + trow + mt * 16 + q * 4) = make_uint2(lo, hi);
    }
  }
}

extern "C" void kernel_launch(void* const* d_in, const int* in_sizes, int n_in,
                              void* d_out, int out_size, void* d_ws, size_t ws_size,
                              hipStream_t stream) {
  (void)in_sizes; (void)n_in; (void)out_size; (void)ws_size;
  const float* query = (const float*)d_in[0];
  const float* key_  = (const float*)d_in[1];
  const float* value = (const float*)d_in[2];
  const float* Wq = (const float*)d_in[3]; const float* bq = (const float*)d_in[4];
  const float* Wk = (const float*)d_in[5]; const float* bk = (const float*)d_in[6];
  const float* Wv = (const float*)d_in[7]; const float* bv = (const float*)d_in[8];
  const float* Wo = (const float*)d_in[9]; const float* bo = (const float*)d_in[10];

  const size_t SZ = (size_t)8192 * 1024;  // elements per (B*T, D) bf16 tensor
  uint16_t* buf0 = (uint16_t*)d_ws;       // qb
  uint16_t* buf1 = buf0 + SZ;             // kb
  uint16_t* buf2 = buf1 + SZ;             // vb -> later attn-out
  uint16_t* buf3 = buf2 + SZ;             // Qp
  uint16_t* wts  = buf3 + SZ;             // 4 x 1M bf16 transposed weights
  uint16_t* Wtq = wts;
  uint16_t* Wtk = wts + 1048576;
  uint16_t* Wtv = wts + 2097152;
  uint16_t* Wto = wts + 3145728;
  uint16_t* Kp  = wts + 4194304;
  uint16_t* Vt  = Kp + SZ;

  const float Cs = 0.125f * LOG2E;  // folded into Q projection

  convert_inputs<<<dim3(4096, 3), 256, 0, stream>>>(query, key_, value, buf0, buf1, buf2);
  transpose_weights<<<dim3(32, 32, 4), 256, 0, stream>>>(Wq, Wk, Wv, Wo, wts);
  gemm_qkv<<<dim3(8, 64, 3), 256, 0, stream>>>(buf0, buf1, buf2, Wtq, Wtk, Wtv,
                                               bq, bk, bv, buf3, Kp, Vt, Cs);
  attn<<<dim3(16, 64), 256, 0, stream>>>(buf3, Kp, Vt, buf2);
  gemm_out<<<dim3(8, 64), 256, 0, stream>>>(buf2, Wto, bo, (float*)d_out);
}

// Round 4
// 329.911 us; speedup vs baseline: 1.0791x; 1.0555x over previous
//
#include <hip/hip_runtime.h>
#include <hip/hip_bf16.h>
#include <stdint.h>

// MHA forward: B=4, T=2048, D=1024, H=16, dk=64.  fp32 in/out, bf16 MFMA internally.
// R3: XOR bank-swizzle on all LDS tiles. R4: softmax de-VALU-ized.
// R6: fused QK->exp->PV per key strip.
// R7: 64-key K/V dbuf tiles, prefetch-after-barrier; XCD-grouping swizzle ->
//     attn FETCH 139->24.6MB, 104.7us.
// R8 lesson: 8 barrier-locked waves regressed (lockstep contention).
// R9 lesson: l-by-MFMA moved work to matrix pipe and attn got SLOWER in
//     proportion (MfmaUtil 42->47, dur +3.8us) -> attn is MFMA-SLOT-bound,
//     and PV at K=16 (16x16x16bf16_1k) burns a full 16x16x32-class slot for
//     half the FLOPs.  Floor check: QK 13.7us + (PV+lacc)@K16-rate 34.4us
//     = 48us = 0.47*108us measured MfmaUtil.  Consistent.
// R10: PV at K=32.  Keys processed in 32-key pairs; QK's A-rows remapped
//     (row m <- key (m>>2)*8+(m&3), second MFMA +4) so lane q's pair outputs
//     are keys q*8..q*8+7 == the exact B-fragment of mfma_f32_16x16x32_bf16.
//     P feeds PV+lacc at K=32, no cross-lane moves.  K staging swizzle changed
//     to g=(r&3)|(((r>>3)&1)<<2) so remapped reads still span all 32 banks.
//     MFMA slots per 64-key tile: 56 -> 36.  kt-loop unrolled x2 (LDS addrs
//     loop-invariant).  Predicted attn ~85us.

typedef __bf16 bf16x8 __attribute__((ext_vector_type(8)));
typedef short  v4s    __attribute__((ext_vector_type(4)));
typedef float  f32x4  __attribute__((ext_vector_type(4)));

#define LOG2E 1.44269504088896340736f

static __device__ __forceinline__ uint32_t f2bf(float x) {
  uint32_t u = __float_as_uint(x);
  u += 0x7fffu + ((u >> 16) & 1u);      // RNE
  return u >> 16;
}
#if __has_builtin(__builtin_amdgcn_cvt_pk_bf16_f32)
static __device__ __forceinline__ uint32_t pk2bf(float a, float b) {
  typedef __bf16 b2 __attribute__((ext_vector_type(2)));
  union { b2 v; uint32_t u; } x;
  x.v = __builtin_amdgcn_cvt_pk_bf16_f32(a, b);  // lo=a, hi=b
  return x.u;
}
#else
static __device__ __forceinline__ uint32_t pk2bf(float a, float b) {
  return f2bf(a) | (f2bf(b) << 16);
}
#endif
static __device__ __forceinline__ void gl2lds16(const void* g, void* l) {
  // async global->LDS, 16B/lane; LDS dest = wave-uniform base + lane*16
  __builtin_amdgcn_global_load_lds(
      (const __attribute__((address_space(1))) uint32_t*)g,
      (__attribute__((address_space(3))) uint32_t*)l, 16, 0, 0);
}

// ---------------- fp32 -> bf16 conversion of q/k/v (8 elems/thread) --------
__global__ void convert_inputs(const float* __restrict__ q, const float* __restrict__ k,
                               const float* __restrict__ v, uint16_t* __restrict__ qo,
                               uint16_t* __restrict__ ko, uint16_t* __restrict__ vo) {
  const float* src = blockIdx.y == 0 ? q : (blockIdx.y == 1 ? k : v);
  uint16_t*    dst = blockIdx.y == 0 ? qo : (blockIdx.y == 1 ? ko : vo);
  size_t idx = ((size_t)blockIdx.x * 256 + threadIdx.x) * 8;
  float4 a = *(const float4*)(src + idx);
  float4 b = *(const float4*)(src + idx + 4);
  uint4 o;
  o.x = pk2bf(a.x, a.y); o.y = pk2bf(a.z, a.w);
  o.z = pk2bf(b.x, b.y); o.w = pk2bf(b.z, b.w);
  *(uint4*)(dst + idx) = o;
}

// ---------------- W (K x N fp32) -> Wt (N x K bf16) ------------------------
__global__ void transpose_weights(const float* __restrict__ Wq, const float* __restrict__ Wk,
                                  const float* __restrict__ Wv, const float* __restrict__ Wo,
                                  uint16_t* __restrict__ out) {
  __shared__ float t[32][33];
  const float* W = blockIdx.z == 0 ? Wq : blockIdx.z == 1 ? Wk : blockIdx.z == 2 ? Wv : Wo;
  uint16_t* O = out + (size_t)blockIdx.z * 1048576;
  int tx = threadIdx.x & 31, ty = threadIdx.x >> 5;
  int r0 = blockIdx.y * 32, c0 = blockIdx.x * 32;
#pragma unroll
  for (int i = 0; i < 4; i++) t[ty + i * 8][tx] = W[(size_t)(r0 + ty + i * 8) * 1024 + c0 + tx];
  __syncthreads();
#pragma unroll
  for (int i = 0; i < 4; i++)
    O[(size_t)(c0 + ty + i * 8) * 1024 + r0 + tx] = (uint16_t)f2bf(t[tx][ty + i * 8]);
}

// ---------------- bf16 GEMM body: C = (A(MxK) * Bt(NxK)^T + bias) * oscale -
// Single-buffered 128x64 LDS tiles (8 chunks of 16B); XOR chunk swizzle by row&7.
// mode 0: fp32 natural   mode 1: bf16 natural   mode 2: bf16 V-transposed per head
static __device__ __forceinline__ void gemm_body(
    const uint16_t* __restrict__ A, const uint16_t* __restrict__ Bt,
    const float* __restrict__ bias, void* __restrict__ Cout,
    int N, int K, int mode, float oscale, int mBase, int nBase,
    uint16_t* __restrict__ lA, uint16_t* __restrict__ lB) {
  int tid = threadIdx.x, wave = tid >> 6, lane = tid & 63;
  int q = lane >> 4, c = lane & 15;
  int wrow = wave & 1, wcol = wave >> 1;
  f32x4 acc[4][4] = {};

  int swz = ((lane & 7) ^ (lane >> 3)) * 8;
  const uint16_t* gA = A + (size_t)(mBase + wave * 32 + (lane >> 3)) * K + swz;
  const uint16_t* gB = Bt + (size_t)(nBase + wave * 32 + (lane >> 3)) * K + swz;
  int cs = c & 7;

  for (int kt = 0; kt < K / 64; kt++) {
    __syncthreads();
    int k0 = kt * 64;
#pragma unroll
    for (int it = 0; it < 4; it++) {
      gl2lds16(gA + (size_t)(it * 8) * K + k0, &lA[(wave * 32 + it * 8) * 64]);
      gl2lds16(gB + (size_t)(it * 8) * K + k0, &lB[(wave * 32 + it * 8) * 64]);
    }
    __syncthreads();
#pragma unroll
    for (int kk = 0; kk < 2; kk++) {
      bf16x8 af[4], bfr[4];
#pragma unroll
      for (int i = 0; i < 4; i++)
        af[i] = *(const bf16x8*)&lA[(wrow * 64 + i * 16 + c) * 64 + ((kk * 4 + q) ^ cs) * 8];
#pragma unroll
      for (int j = 0; j < 4; j++)
        bfr[j] = *(const bf16x8*)&lB[(wcol * 64 + j * 16 + c) * 64 + ((kk * 4 + q) ^ cs) * 8];
#pragma unroll
      for (int i = 0; i < 4; i++)
#pragma unroll
        for (int j = 0; j < 4; j++)
          acc[i][j] = __builtin_amdgcn_mfma_f32_16x16x32_bf16(af[i], bfr[j], acc[i][j], 0, 0, 0);
    }
  }

  float bb[4];
#pragma unroll
  for (int j = 0; j < 4; j++) bb[j] = bias[nBase + wcol * 64 + j * 16 + c];

  if (mode == 0) {
    float* Co = (float*)Cout;
#pragma unroll
    for (int i = 0; i < 4; i++)
#pragma unroll
      for (int j = 0; j < 4; j++) {
        int row = mBase + wrow * 64 + i * 16 + q * 4;
        int col = nBase + wcol * 64 + j * 16 + c;
#pragma unroll
        for (int r = 0; r < 4; r++) Co[(size_t)(row + r) * N + col] = acc[i][j][r] + bb[j];
      }
  } else if (mode == 1) {
    uint16_t* Co = (uint16_t*)Cout;
#pragma unroll
    for (int i = 0; i < 4; i++)
#pragma unroll
      for (int j = 0; j < 4; j++) {
        int row = mBase + wrow * 64 + i * 16 + q * 4;
        int col = nBase + wcol * 64 + j * 16 + c;
#pragma unroll
        for (int r = 0; r < 4; r++)
          Co[(size_t)(row + r) * N + col] = (uint16_t)f2bf((acc[i][j][r] + bb[j]) * oscale);
      }
  } else {  // V: write Vt[(b*16+h)*64+d][t]
    uint16_t* Co = (uint16_t*)Cout;
#pragma unroll
    for (int i = 0; i < 4; i++)
#pragma unroll
      for (int j = 0; j < 4; j++) {
        int n = nBase + wcol * 64 + j * 16 + c;
        int h = n >> 6, d = n & 63;
        int m = mBase + wrow * 64 + i * 16 + q * 4;
        int b = m >> 11, t = m & 2047;
        uint32_t lo = pk2bf(acc[i][j][0] + bb[j], acc[i][j][1] + bb[j]);
        uint32_t hi = pk2bf(acc[i][j][2] + bb[j], acc[i][j][3] + bb[j]);
        *(uint2*)(Co + (size_t)((b * 16 + h) * 64 + d) * 2048 + t) = make_uint2(lo, hi);
      }
  }
}

// Q/K/V projections batched: grid (8, 64, 3).  XCD-grouping swizzle: XCD k owns
// A-row-panels y in [8k,8k+8) for all (x,z), so each 256KB A panel is fetched by
// one XCD's L2 instead of 8.
__global__ __launch_bounds__(256, 2)
void gemm_qkv(const uint16_t* __restrict__ qb, const uint16_t* __restrict__ kb,
              const uint16_t* __restrict__ vb, const uint16_t* __restrict__ Wtq,
              const uint16_t* __restrict__ Wtk, const uint16_t* __restrict__ Wtv,
              const float* __restrict__ bq, const float* __restrict__ bk,
              const float* __restrict__ bv, uint16_t* __restrict__ Qp,
              uint16_t* __restrict__ Kp, uint16_t* __restrict__ Vt, float cs) {
  __shared__ uint16_t lA[8192], lB[8192];
  int id = blockIdx.x + (blockIdx.y << 3) + (blockIdx.z << 9);  // 0..1535
  int xcd = id & 7, j = id >> 3;                                // j: 0..191
  int by = xcd * 8 + (j & 7);
  int bx = (j >> 3) & 7;
  int z  = j >> 6;
  const uint16_t* A  = z == 0 ? qb : (z == 1 ? kb : vb);
  const uint16_t* Bt = z == 0 ? Wtq : (z == 1 ? Wtk : Wtv);
  const float* bias  = z == 0 ? bq : (z == 1 ? bk : bv);
  void* C            = z == 0 ? (void*)Qp : (z == 1 ? (void*)Kp : (void*)Vt);
  int mode   = z == 2 ? 2 : 1;
  float os   = z == 0 ? cs : 1.0f;
  gemm_body(A, Bt, bias, C, 1024, 1024, mode, os, by * 128, bx * 128, lA, lB);
}

__global__ __launch_bounds__(256, 2)
void gemm_out(const uint16_t* __restrict__ A, const uint16_t* __restrict__ Bt,
              const float* __restrict__ bias, float* __restrict__ C) {
  __shared__ uint16_t lA[8192], lB[8192];
  int id = blockIdx.x + (blockIdx.y << 3);  // 0..511
  int xcd = id & 7, j = id >> 3;            // j: 0..63
  int by = xcd * 8 + (j & 7);
  int bx = j >> 3;
  gemm_body(A, Bt, bias, C, 1024, 1024, 0, 1.0f, by * 128, bx * 128, lA, lB);
}

// ---------------- flash attention ------------------------------------------
// grid (16, 64), 256 threads (4 waves).  XCD swizzle: XCD k owns bh in
// [8k,8k+8) (its K+V = 4MB = its L2).  S^T = K*Q^T; Q pre-scaled by
// 0.125*log2e -> p = exp2(s), no online max.
// 64-key K/V tiles double-buffered in 32KiB:
//   lds[    0.. 4096) = K buf0    lds[ 4096.. 8192) = K buf1
//   lds[ 8192..12288) = V buf0    lds[12288..16384) = V buf1
// R10 key-pair structure: per 32-key pair, QK MFMA-A takes A-row m from key
// (m>>2)*8+(m&3), MFMA-B from +4.  Lane (q,c) then holds P for keys q*8..q*8+7
// across its 8 output regs == the B-fragment of mfma_f32_16x16x32_bf16, so PV
// and the l-accumulator run at K=32 (full rate).  K LDS uses swizzle
// g(r)=(r&3)|(((r>>3)&1)<<2) (spans all banks under the remapped read); V keeps
// the r&7 swizzle, read b128 at chunk (pair*4+q)^cs.
__global__ __launch_bounds__(256, 2)
void attn(const uint16_t* __restrict__ Qp, const uint16_t* __restrict__ Kp,
          const uint16_t* __restrict__ Vt, uint16_t* __restrict__ Ob) {
  __shared__ uint16_t lds[16384];
  int tid = threadIdx.x, wave = tid >> 6, lane = tid & 63;
  int q = lane >> 4, c = lane & 15;
  int cs = c & 7;
  int gq   = (c & 3) | (((c >> 2) & 1) << 2);  // K-read swizzle term
  int rowA = ((c >> 2) << 3) + (c & 3);        // K row within 32-key pair (MFMA-A)

  int id = blockIdx.y * 16 + blockIdx.x;     // 0..1023
  int wk = (id & 7) * 128 + (id >> 3);       // bijective XCD grouping
  int qt = wk & 15, bh = wk >> 4;
  int b = bh >> 4, h = bh & 15;
  int qbase = qt * 128;
  int swz = ((lane & 7) ^ (lane >> 3)) * 8;  // r&7 swizzle (Q and V staging)

  {  // stage Q tile (128 x 64) into lds[0..8192), r&7-swizzled
    const uint16_t* gQ =
        Qp + (size_t)(b * 2048 + qbase + wave * 32 + (lane >> 3)) * 1024 + h * 64 + swz;
#pragma unroll
    for (int it = 0; it < 4; it++)
      gl2lds16(gQ + (size_t)(it * 8) * 1024, &lds[(wave * 32 + it * 8) * 64]);
  }
  __syncthreads();
  bf16x8 qf[2][2];
#pragma unroll
  for (int it = 0; it < 2; it++)
#pragma unroll
    for (int kk = 0; kk < 2; kk++)
      qf[it][kk] =
          *(const bf16x8*)&lds[(wave * 32 + it * 16 + c) * 64 + ((kk * 4 + q) ^ cs) * 8];
  __syncthreads();  // all waves' qf reads done before K tile 0 overwrites Q

  f32x4 o[4][2] = {};
  f32x4 lacc[2] = {};
  union { uint32_t u[4]; bf16x8 v; } one8;
  one8.u[0] = one8.u[1] = one8.u[2] = one8.u[3] = 0x3F803F80u;  // bf16 1.0 x8

  // K staging with g-swizzle: wave stages rows wave*16+it*8+rho; content chunk
  // at position p is p ^ ((rho&3) | (it<<2)).
  int kchunk = (lane & 7) ^ ((lane >> 3) & 3);
  const uint16_t* gKa =
      Kp + (size_t)(b * 2048 + wave * 16 + (lane >> 3)) * 1024 + h * 64 + kchunk * 8;
  const uint16_t* gKb =
      Kp + (size_t)(b * 2048 + wave * 16 + 8 + (lane >> 3)) * 1024 + h * 64 + (kchunk ^ 4) * 8;
  const uint16_t* gV0 = Vt + (size_t)(bh * 64 + wave * 16 + (lane >> 3)) * 2048 + swz;

  auto stage = [&](int tile, int nb) {
    gl2lds16(gKa + (size_t)(tile * 64) * 1024, &lds[nb + (wave * 16) * 64]);
    gl2lds16(gKb + (size_t)(tile * 64) * 1024, &lds[nb + (wave * 16 + 8) * 64]);
    gl2lds16(gV0 + (size_t)(tile * 64), &lds[8192 + nb + (wave * 16) * 64]);
    gl2lds16(gV0 + (size_t)(8 * 2048) + tile * 64, &lds[8192 + nb + (wave * 16 + 8) * 64]);
  };

  auto compute = [&](const uint16_t* sKc, const uint16_t* sVc) {
    f32x4 s[2][2][2];  // [pair][keyhalf A/B][query-half it]
#pragma unroll
    for (int p = 0; p < 2; p++) {
      const uint16_t* kr = &sKc[(p * 32 + rowA) * 64];
      bf16x8 aA0 = *(const bf16x8*)&kr[(q ^ gq) * 8];
      bf16x8 aA1 = *(const bf16x8*)&kr[((4 + q) ^ gq) * 8];
      bf16x8 aB0 = *(const bf16x8*)&kr[256 + (q ^ gq) * 8];
      bf16x8 aB1 = *(const bf16x8*)&kr[256 + ((4 + q) ^ gq) * 8];
      s[p][0][0] = __builtin_amdgcn_mfma_f32_16x16x32_bf16(aA0, qf[0][0],
                                                           (f32x4){0.f, 0.f, 0.f, 0.f}, 0, 0, 0);
      s[p][0][0] = __builtin_amdgcn_mfma_f32_16x16x32_bf16(aA1, qf[0][1], s[p][0][0], 0, 0, 0);
      s[p][0][1] = __builtin_amdgcn_mfma_f32_16x16x32_bf16(aA0, qf[1][0],
                                                           (f32x4){0.f, 0.f, 0.f, 0.f}, 0, 0, 0);
      s[p][0][1] = __builtin_amdgcn_mfma_f32_16x16x32_bf16(aA1, qf[1][1], s[p][0][1], 0, 0, 0);
      s[p][1][0] = __builtin_amdgcn_mfma_f32_16x16x32_bf16(aB0, qf[0][0],
                                                           (f32x4){0.f, 0.f, 0.f, 0.f}, 0, 0, 0);
      s[p][1][0] = __builtin_amdgcn_mfma_f32_16x16x32_bf16(aB1, qf[0][1], s[p][1][0], 0, 0, 0);
      s[p][1][1] = __builtin_amdgcn_mfma_f32_16x16x32_bf16(aB0, qf[1][0],
                                                           (f32x4){0.f, 0.f, 0.f, 0.f}, 0, 0, 0);
      s[p][1][1] = __builtin_amdgcn_mfma_f32_16x16x32_bf16(aB1, qf[1][1], s[p][1][1], 0, 0, 0);
    }
#pragma unroll
    for (int p = 0; p < 2; p++) {
      union { uint32_t u[4]; bf16x8 v; } pb[2];
#pragma unroll
      for (int it = 0; it < 2; it++) {
        float a0 = __builtin_amdgcn_exp2f(s[p][0][it][0]);
        float a1 = __builtin_amdgcn_exp2f(s[p][0][it][1]);
        float a2 = __builtin_amdgcn_exp2f(s[p][0][it][2]);
        float a3 = __builtin_amdgcn_exp2f(s[p][0][it][3]);
        float b0 = __builtin_amdgcn_exp2f(s[p][1][it][0]);
        float b1 = __builtin_amdgcn_exp2f(s[p][1][it][1]);
        float b2 = __builtin_amdgcn_exp2f(s[p][1][it][2]);
        float b3 = __builtin_amdgcn_exp2f(s[p][1][it][3]);
        pb[it].u[0] = pk2bf(a0, a1); pb[it].u[1] = pk2bf(a2, a3);
        pb[it].u[2] = pk2bf(b0, b1); pb[it].u[3] = pk2bf(b2, b3);
      }
      // softmax denominator on the MFMA pipe at K=32
      lacc[0] = __builtin_amdgcn_mfma_f32_16x16x32_bf16(one8.v, pb[0].v, lacc[0], 0, 0, 0);
      lacc[1] = __builtin_amdgcn_mfma_f32_16x16x32_bf16(one8.v, pb[1].v, lacc[1], 0, 0, 0);
#pragma unroll
      for (int mt = 0; mt < 4; mt++) {
        bf16x8 vv = *(const bf16x8*)&sVc[(mt * 16 + c) * 64 + (((p * 4 + q) ^ cs) * 8)];
        o[mt][0] = __builtin_amdgcn_mfma_f32_16x16x32_bf16(vv, pb[0].v, o[mt][0], 0, 0, 0);
        o[mt][1] = __builtin_amdgcn_mfma_f32_16x16x32_bf16(vv, pb[1].v, o[mt][1], 0, 0, 0);
      }
    }
  };

  stage(0, 0);  // prologue: tile 0 -> buf 0
  for (int kt2 = 0; kt2 < 16; kt2++) {
    __syncthreads();                       // tile 2*kt2 resident in buf0
    stage(kt2 * 2 + 1, 4096);              // prefetch odd tile -> buf1
    compute(&lds[0], &lds[8192]);
    __syncthreads();                       // tile 2*kt2+1 resident in buf1
    if (kt2 < 15) stage(kt2 * 2 + 2, 0);   // prefetch even tile -> buf0
    compute(&lds[4096], &lds[12288]);
  }

  // l = column sums (all rows/regs of lacc identical) -- no shuffles needed
  float l[2] = {lacc[0][0], lacc[1][0]};

  // epilogue: attn[t][h*64+d] bf16, 4 consecutive d per 8B store
#pragma unroll
  for (int it = 0; it < 2; it++) {
    float inv = 1.0f / l[it];
    size_t trow = (size_t)(b * 2048 + qbase + wave * 32 + it * 16 + c) * 1024 + h * 64;
#pragma unroll
    for (int mt = 0; mt < 4; mt++) {
      uint32_t lo = pk2bf(o[mt][it][0] * inv, o[mt][it][1] * inv);
      uint32_t hi = pk2bf(o[mt][it][2] * inv, o[mt][it][3] * inv);
      *(uint2*)(Ob + trow + mt * 16 + q * 4) = make_uint2(lo, hi);
    }
  }
}

extern "C" void kernel_launch(void* const* d_in, const int* in_sizes, int n_in,
                              void* d_out, int out_size, void* d_ws, size_t ws_size,
                              hipStream_t stream) {
  (void)in_sizes; (void)n_in; (void)out_size; (void)ws_size;
  const float* query = (const float*)d_in[0];
  const float* key_  = (const float*)d_in[1];
  const float* value = (const float*)d_in[2];
  const float* Wq = (const float*)d_in[3]; const float* bq = (const float*)d_in[4];
  const float* Wk = (const float*)d_in[5]; const float* bk = (const float*)d_in[6];
  const float* Wv = (const float*)d_in[7]; const float* bv = (const float*)d_in[8];
  const float* Wo = (const float*)d_in[9]; const float* bo = (const float*)d_in[10];

  const size_t SZ = (size_t)8192 * 1024;  // elements per (B*T, D) bf16 tensor
  uint16_t* buf0 = (uint16_t*)d_ws;       // qb
  uint16_t* buf1 = buf0 + SZ;             // kb
  uint16_t* buf2 = buf1 + SZ;             // vb -> later attn-out
  uint16_t* buf3 = buf2 + SZ;             // Qp
  uint16_t* wts  = buf3 + SZ;             // 4 x 1M bf16 transposed weights
  uint16_t* Wtq = wts;
  uint16_t* Wtk = wts + 1048576;
  uint16_t* Wtv = wts + 2097152;
  uint16_t* Wto = wts + 3145728;
  uint16_t* Kp  = wts + 4194304;
  uint16_t* Vt  = Kp + SZ;

  const float Cs = 0.125f * LOG2E;  // folded into Q projection

  convert_inputs<<<dim3(4096, 3), 256, 0, stream>>>(query, key_, value, buf0, buf1, buf2);
  transpose_weights<<<dim3(32, 32, 4), 256, 0, stream>>>(Wq, Wk, Wv, Wo, wts);
  gemm_qkv<<<dim3(8, 64, 3), 256, 0, stream>>>(buf0, buf1, buf2, Wtq, Wtk, Wtv,
                                               bq, bk, bv, buf3, Kp, Vt, Cs);
  attn<<<dim3(16, 64), 256, 0, stream>>>(buf3, Kp, Vt, buf2);
  gemm_out<<<dim3(8, 64), 256, 0, stream>>>(buf2, Wto, bo, (float*)d_out);
}

// Round 5
// 321.402 us; speedup vs baseline: 1.1076x; 1.0265x over previous
//
#include <hip/hip_runtime.h>
#include <hip/hip_bf16.h>
#include <stdint.h>

// MHA forward: B=4, T=2048, D=1024, H=16, dk=64.  fp32 in/out, bf16 MFMA internally.
// R3: XOR bank-swizzle on all LDS tiles. R4: softmax de-VALU-ized.
// R7: 64-key K/V dbuf tiles, prefetch-after-barrier; XCD-grouping swizzle.
// R8 lesson: 8 barrier-locked waves regressed (lockstep contention).
// R10: PV at K=32 via key-pair remap -> attn 108.5->87.3us, bank conflicts 0,
//      MfmaUtil*dur == full-rate MFMA floor (33us).  Confirmed MFMA-slot model.
// R11: attn is now bound by MFMA(33us) + LDS-read(27us) + VALU(~17us) summing
//      to the wall.  LDS bytes/query is the reducible term: double the
//      per-wave query blocking (qf[4][2], 64 q/wave, 256 q/block, grid 16->8).
//      K/V LDS reads, gl2lds count, and barriers PER QUERY all halve; MFMA and
//      exp per query unchanged.  Keeps the proven 4-wave barrier structure
//      (unlike R8).  VGPR ~190 expected; failure mode = spill.

typedef __bf16 bf16x8 __attribute__((ext_vector_type(8)));
typedef short  v4s    __attribute__((ext_vector_type(4)));
typedef float  f32x4  __attribute__((ext_vector_type(4)));

#define LOG2E 1.44269504088896340736f

static __device__ __forceinline__ uint32_t f2bf(float x) {
  uint32_t u = __float_as_uint(x);
  u += 0x7fffu + ((u >> 16) & 1u);      // RNE
  return u >> 16;
}
#if __has_builtin(__builtin_amdgcn_cvt_pk_bf16_f32)
static __device__ __forceinline__ uint32_t pk2bf(float a, float b) {
  typedef __bf16 b2 __attribute__((ext_vector_type(2)));
  union { b2 v; uint32_t u; } x;
  x.v = __builtin_amdgcn_cvt_pk_bf16_f32(a, b);  // lo=a, hi=b
  return x.u;
}
#else
static __device__ __forceinline__ uint32_t pk2bf(float a, float b) {
  return f2bf(a) | (f2bf(b) << 16);
}
#endif
static __device__ __forceinline__ void gl2lds16(const void* g, void* l) {
  // async global->LDS, 16B/lane; LDS dest = wave-uniform base + lane*16
  __builtin_amdgcn_global_load_lds(
      (const __attribute__((address_space(1))) uint32_t*)g,
      (__attribute__((address_space(3))) uint32_t*)l, 16, 0, 0);
}

// ---------------- fp32 -> bf16 conversion of q/k/v (8 elems/thread) --------
__global__ void convert_inputs(const float* __restrict__ q, const float* __restrict__ k,
                               const float* __restrict__ v, uint16_t* __restrict__ qo,
                               uint16_t* __restrict__ ko, uint16_t* __restrict__ vo) {
  const float* src = blockIdx.y == 0 ? q : (blockIdx.y == 1 ? k : v);
  uint16_t*    dst = blockIdx.y == 0 ? qo : (blockIdx.y == 1 ? ko : vo);
  size_t idx = ((size_t)blockIdx.x * 256 + threadIdx.x) * 8;
  float4 a = *(const float4*)(src + idx);
  float4 b = *(const float4*)(src + idx + 4);
  uint4 o;
  o.x = pk2bf(a.x, a.y); o.y = pk2bf(a.z, a.w);
  o.z = pk2bf(b.x, b.y); o.w = pk2bf(b.z, b.w);
  *(uint4*)(dst + idx) = o;
}

// ---------------- W (K x N fp32) -> Wt (N x K bf16) ------------------------
__global__ void transpose_weights(const float* __restrict__ Wq, const float* __restrict__ Wk,
                                  const float* __restrict__ Wv, const float* __restrict__ Wo,
                                  uint16_t* __restrict__ out) {
  __shared__ float t[32][33];
  const float* W = blockIdx.z == 0 ? Wq : blockIdx.z == 1 ? Wk : blockIdx.z == 2 ? Wv : Wo;
  uint16_t* O = out + (size_t)blockIdx.z * 1048576;
  int tx = threadIdx.x & 31, ty = threadIdx.x >> 5;
  int r0 = blockIdx.y * 32, c0 = blockIdx.x * 32;
#pragma unroll
  for (int i = 0; i < 4; i++) t[ty + i * 8][tx] = W[(size_t)(r0 + ty + i * 8) * 1024 + c0 + tx];
  __syncthreads();
#pragma unroll
  for (int i = 0; i < 4; i++)
    O[(size_t)(c0 + ty + i * 8) * 1024 + r0 + tx] = (uint16_t)f2bf(t[tx][ty + i * 8]);
}

// ---------------- bf16 GEMM body: C = (A(MxK) * Bt(NxK)^T + bias) * oscale -
// Single-buffered 128x64 LDS tiles (8 chunks of 16B); XOR chunk swizzle by row&7.
// mode 0: fp32 natural   mode 1: bf16 natural   mode 2: bf16 V-transposed per head
static __device__ __forceinline__ void gemm_body(
    const uint16_t* __restrict__ A, const uint16_t* __restrict__ Bt,
    const float* __restrict__ bias, void* __restrict__ Cout,
    int N, int K, int mode, float oscale, int mBase, int nBase,
    uint16_t* __restrict__ lA, uint16_t* __restrict__ lB) {
  int tid = threadIdx.x, wave = tid >> 6, lane = tid & 63;
  int q = lane >> 4, c = lane & 15;
  int wrow = wave & 1, wcol = wave >> 1;
  f32x4 acc[4][4] = {};

  int swz = ((lane & 7) ^ (lane >> 3)) * 8;
  const uint16_t* gA = A + (size_t)(mBase + wave * 32 + (lane >> 3)) * K + swz;
  const uint16_t* gB = Bt + (size_t)(nBase + wave * 32 + (lane >> 3)) * K + swz;
  int cs = c & 7;

  for (int kt = 0; kt < K / 64; kt++) {
    __syncthreads();
    int k0 = kt * 64;
#pragma unroll
    for (int it = 0; it < 4; it++) {
      gl2lds16(gA + (size_t)(it * 8) * K + k0, &lA[(wave * 32 + it * 8) * 64]);
      gl2lds16(gB + (size_t)(it * 8) * K + k0, &lB[(wave * 32 + it * 8) * 64]);
    }
    __syncthreads();
#pragma unroll
    for (int kk = 0; kk < 2; kk++) {
      bf16x8 af[4], bfr[4];
#pragma unroll
      for (int i = 0; i < 4; i++)
        af[i] = *(const bf16x8*)&lA[(wrow * 64 + i * 16 + c) * 64 + ((kk * 4 + q) ^ cs) * 8];
#pragma unroll
      for (int j = 0; j < 4; j++)
        bfr[j] = *(const bf16x8*)&lB[(wcol * 64 + j * 16 + c) * 64 + ((kk * 4 + q) ^ cs) * 8];
#pragma unroll
      for (int i = 0; i < 4; i++)
#pragma unroll
        for (int j = 0; j < 4; j++)
          acc[i][j] = __builtin_amdgcn_mfma_f32_16x16x32_bf16(af[i], bfr[j], acc[i][j], 0, 0, 0);
    }
  }

  float bb[4];
#pragma unroll
  for (int j = 0; j < 4; j++) bb[j] = bias[nBase + wcol * 64 + j * 16 + c];

  if (mode == 0) {
    float* Co = (float*)Cout;
#pragma unroll
    for (int i = 0; i < 4; i++)
#pragma unroll
      for (int j = 0; j < 4; j++) {
        int row = mBase + wrow * 64 + i * 16 + q * 4;
        int col = nBase + wcol * 64 + j * 16 + c;
#pragma unroll
        for (int r = 0; r < 4; r++) Co[(size_t)(row + r) * N + col] = acc[i][j][r] + bb[j];
      }
  } else if (mode == 1) {
    uint16_t* Co = (uint16_t*)Cout;
#pragma unroll
    for (int i = 0; i < 4; i++)
#pragma unroll
      for (int j = 0; j < 4; j++) {
        int row = mBase + wrow * 64 + i * 16 + q * 4;
        int col = nBase + wcol * 64 + j * 16 + c;
#pragma unroll
        for (int r = 0; r < 4; r++)
          Co[(size_t)(row + r) * N + col] = (uint16_t)f2bf((acc[i][j][r] + bb[j]) * oscale);
      }
  } else {  // V: write Vt[(b*16+h)*64+d][t]
    uint16_t* Co = (uint16_t*)Cout;
#pragma unroll
    for (int i = 0; i < 4; i++)
#pragma unroll
      for (int j = 0; j < 4; j++) {
        int n = nBase + wcol * 64 + j * 16 + c;
        int h = n >> 6, d = n & 63;
        int m = mBase + wrow * 64 + i * 16 + q * 4;
        int b = m >> 11, t = m & 2047;
        uint32_t lo = pk2bf(acc[i][j][0] + bb[j], acc[i][j][1] + bb[j]);
        uint32_t hi = pk2bf(acc[i][j][2] + bb[j], acc[i][j][3] + bb[j]);
        *(uint2*)(Co + (size_t)((b * 16 + h) * 64 + d) * 2048 + t) = make_uint2(lo, hi);
      }
  }
}

// Q/K/V projections batched: grid (8, 64, 3).  XCD-grouping swizzle: XCD k owns
// A-row-panels y in [8k,8k+8) for all (x,z), so each 256KB A panel is fetched by
// one XCD's L2 instead of 8.
__global__ __launch_bounds__(256, 2)
void gemm_qkv(const uint16_t* __restrict__ qb, const uint16_t* __restrict__ kb,
              const uint16_t* __restrict__ vb, const uint16_t* __restrict__ Wtq,
              const uint16_t* __restrict__ Wtk, const uint16_t* __restrict__ Wtv,
              const float* __restrict__ bq, const float* __restrict__ bk,
              const float* __restrict__ bv, uint16_t* __restrict__ Qp,
              uint16_t* __restrict__ Kp, uint16_t* __restrict__ Vt, float cs) {
  __shared__ uint16_t lA[8192], lB[8192];
  int id = blockIdx.x + (blockIdx.y << 3) + (blockIdx.z << 9);  // 0..1535
  int xcd = id & 7, j = id >> 3;                                // j: 0..191
  int by = xcd * 8 + (j & 7);
  int bx = (j >> 3) & 7;
  int z  = j >> 6;
  const uint16_t* A  = z == 0 ? qb : (z == 1 ? kb : vb);
  const uint16_t* Bt = z == 0 ? Wtq : (z == 1 ? Wtk : Wtv);
  const float* bias  = z == 0 ? bq : (z == 1 ? bk : bv);
  void* C            = z == 0 ? (void*)Qp : (z == 1 ? (void*)Kp : (void*)Vt);
  int mode   = z == 2 ? 2 : 1;
  float os   = z == 0 ? cs : 1.0f;
  gemm_body(A, Bt, bias, C, 1024, 1024, mode, os, by * 128, bx * 128, lA, lB);
}

__global__ __launch_bounds__(256, 2)
void gemm_out(const uint16_t* __restrict__ A, const uint16_t* __restrict__ Bt,
              const float* __restrict__ bias, float* __restrict__ C) {
  __shared__ uint16_t lA[8192], lB[8192];
  int id = blockIdx.x + (blockIdx.y << 3);  // 0..511
  int xcd = id & 7, j = id >> 3;            // j: 0..63
  int by = xcd * 8 + (j & 7);
  int bx = j >> 3;
  gemm_body(A, Bt, bias, C, 1024, 1024, 0, 1.0f, by * 128, bx * 128, lA, lB);
}

// ---------------- flash attention ------------------------------------------
// grid (8, 64), 256 threads (4 waves), 256 queries/block (64 per wave).
// XCD swizzle: XCD k owns bh in [8k,8k+8) (its K+V = 4MB = its L2).
// S^T = K*Q^T; Q pre-scaled by 0.125*log2e -> p = exp2(s), no online max.
// 64-key K/V tiles double-buffered in 32KiB:
//   lds[    0.. 4096) = K buf0    lds[ 4096.. 8192) = K buf1
//   lds[ 8192..12288) = V buf0    lds[12288..16384) = V buf1
// (whole LDS holds the 256x64 Q tile during the prologue).
// R10 key-pair structure: per 32-key pair, QK MFMA-A takes A-row m from key
// (m>>2)*8+(m&3), second MFMA +4.  Lane (q,c) then holds P for keys q*8..q*8+7
// == the B-fragment of mfma_f32_16x16x32_bf16, so PV and lacc run at K=32.
// R11: qf[4][2] -> each wave owns 64 queries; K/V LDS reads, staging, and
// barriers per query are HALVED vs R10.  MFMA/exp per query unchanged.
__global__ __launch_bounds__(256, 2)
void attn(const uint16_t* __restrict__ Qp, const uint16_t* __restrict__ Kp,
          const uint16_t* __restrict__ Vt, uint16_t* __restrict__ Ob) {
  __shared__ uint16_t lds[16384];
  int tid = threadIdx.x, wave = tid >> 6, lane = tid & 63;
  int q = lane >> 4, c = lane & 15;
  int cs = c & 7;
  int gq   = (c & 3) | (((c >> 2) & 1) << 2);  // K-read swizzle term
  int rowA = ((c >> 2) << 3) + (c & 3);        // K row within 32-key pair (MFMA-A)

  int id = blockIdx.y * 8 + blockIdx.x;      // 0..511
  int wk = (id & 7) * 64 + (id >> 3);        // bijective XCD grouping
  int qt = wk & 7, bh = wk >> 3;
  int b = bh >> 4, h = bh & 15;
  int qbase = qt * 256;
  int swz = ((lane & 7) ^ (lane >> 3)) * 8;  // r&7 swizzle (Q and V staging)

  {  // stage Q tile (256 x 64) into the whole LDS, r&7-swizzled
    const uint16_t* gQ =
        Qp + (size_t)(b * 2048 + qbase + wave * 64 + (lane >> 3)) * 1024 + h * 64 + swz;
#pragma unroll
    for (int it = 0; it < 8; it++)
      gl2lds16(gQ + (size_t)(it * 8) * 1024, &lds[(wave * 64 + it * 8) * 64]);
  }
  __syncthreads();
  bf16x8 qf[4][2];
#pragma unroll
  for (int it = 0; it < 4; it++)
#pragma unroll
    for (int kk = 0; kk < 2; kk++)
      qf[it][kk] =
          *(const bf16x8*)&lds[(wave * 64 + it * 16 + c) * 64 + ((kk * 4 + q) ^ cs) * 8];
  __syncthreads();  // all waves' qf reads done before K tile 0 overwrites Q

  f32x4 o[4][4] = {};
  f32x4 lacc[4] = {};
  union { uint32_t u[4]; bf16x8 v; } one8;
  one8.u[0] = one8.u[1] = one8.u[2] = one8.u[3] = 0x3F803F80u;  // bf16 1.0 x8

  // K staging with g-swizzle: wave stages rows wave*16+it*8+rho; content chunk
  // at position p is p ^ ((rho&3) | (it<<2)).
  int kchunk = (lane & 7) ^ ((lane >> 3) & 3);
  const uint16_t* gKa =
      Kp + (size_t)(b * 2048 + wave * 16 + (lane >> 3)) * 1024 + h * 64 + kchunk * 8;
  const uint16_t* gKb =
      Kp + (size_t)(b * 2048 + wave * 16 + 8 + (lane >> 3)) * 1024 + h * 64 + (kchunk ^ 4) * 8;
  const uint16_t* gV0 = Vt + (size_t)(bh * 64 + wave * 16 + (lane >> 3)) * 2048 + swz;

  auto stage = [&](int tile, int nb) {
    gl2lds16(gKa + (size_t)(tile * 64) * 1024, &lds[nb + (wave * 16) * 64]);
    gl2lds16(gKb + (size_t)(tile * 64) * 1024, &lds[nb + (wave * 16 + 8) * 64]);
    gl2lds16(gV0 + (size_t)(tile * 64), &lds[8192 + nb + (wave * 16) * 64]);
    gl2lds16(gV0 + (size_t)(8 * 2048) + tile * 64, &lds[8192 + nb + (wave * 16 + 8) * 64]);
  };

  auto compute = [&](const uint16_t* sKc, const uint16_t* sVc) {
#pragma unroll
    for (int p = 0; p < 2; p++) {
      const uint16_t* kr = &sKc[(p * 32 + rowA) * 64];
      bf16x8 aA0 = *(const bf16x8*)&kr[(q ^ gq) * 8];
      bf16x8 aA1 = *(const bf16x8*)&kr[((4 + q) ^ gq) * 8];
      bf16x8 aB0 = *(const bf16x8*)&kr[256 + (q ^ gq) * 8];
      bf16x8 aB1 = *(const bf16x8*)&kr[256 + ((4 + q) ^ gq) * 8];
      f32x4 sA[4], sB[4];
#pragma unroll
      for (int it = 0; it < 4; it++) {
        sA[it] = __builtin_amdgcn_mfma_f32_16x16x32_bf16(aA0, qf[it][0],
                                                         (f32x4){0.f, 0.f, 0.f, 0.f}, 0, 0, 0);
        sA[it] = __builtin_amdgcn_mfma_f32_16x16x32_bf16(aA1, qf[it][1], sA[it], 0, 0, 0);
        sB[it] = __builtin_amdgcn_mfma_f32_16x16x32_bf16(aB0, qf[it][0],
                                                         (f32x4){0.f, 0.f, 0.f, 0.f}, 0, 0, 0);
        sB[it] = __builtin_amdgcn_mfma_f32_16x16x32_bf16(aB1, qf[it][1], sB[it], 0, 0, 0);
      }
      union { uint32_t u[4]; bf16x8 v; } pb[4];
#pragma unroll
      for (int it = 0; it < 4; it++) {
        float a0 = __builtin_amdgcn_exp2f(sA[it][0]);
        float a1 = __builtin_amdgcn_exp2f(sA[it][1]);
        float a2 = __builtin_amdgcn_exp2f(sA[it][2]);
        float a3 = __builtin_amdgcn_exp2f(sA[it][3]);
        float b0 = __builtin_amdgcn_exp2f(sB[it][0]);
        float b1 = __builtin_amdgcn_exp2f(sB[it][1]);
        float b2 = __builtin_amdgcn_exp2f(sB[it][2]);
        float b3 = __builtin_amdgcn_exp2f(sB[it][3]);
        pb[it].u[0] = pk2bf(a0, a1); pb[it].u[1] = pk2bf(a2, a3);
        pb[it].u[2] = pk2bf(b0, b1); pb[it].u[3] = pk2bf(b2, b3);
      }
      // softmax denominator on the MFMA pipe at K=32
#pragma unroll
      for (int it = 0; it < 4; it++)
        lacc[it] = __builtin_amdgcn_mfma_f32_16x16x32_bf16(one8.v, pb[it].v, lacc[it], 0, 0, 0);
#pragma unroll
      for (int mt = 0; mt < 4; mt++) {
        bf16x8 vv = *(const bf16x8*)&sVc[(mt * 16 + c) * 64 + (((p * 4 + q) ^ cs) * 8)];
#pragma unroll
        for (int it = 0; it < 4; it++)
          o[mt][it] = __builtin_amdgcn_mfma_f32_16x16x32_bf16(vv, pb[it].v, o[mt][it], 0, 0, 0);
      }
    }
  };

  stage(0, 0);  // prologue: tile 0 -> buf 0
  for (int kt2 = 0; kt2 < 16; kt2++) {
    __syncthreads();                       // tile 2*kt2 resident in buf0
    stage(kt2 * 2 + 1, 4096);              // prefetch odd tile -> buf1
    compute(&lds[0], &lds[8192]);
    __syncthreads();                       // tile 2*kt2+1 resident in buf1
    if (kt2 < 15) stage(kt2 * 2 + 2, 0);   // prefetch even tile -> buf0
    compute(&lds[4096], &lds[12288]);
  }

  // l = column sums (all rows/regs of lacc identical) -- no shuffles needed
  // epilogue: attn[t][h*64+d] bf16, 4 consecutive d per 8B store
#pragma unroll
  for (int it = 0; it < 4; it++) {
    float inv = 1.0f / lacc[it][0];
    size_t trow = (size_t)(b * 2048 + qbase + wave * 64 + it * 16 + c) * 1024 + h * 64;
#pragma unroll
    for (int mt = 0; mt < 4; mt++) {
      uint32_t lo = pk2bf(o[mt][it][0] * inv, o[mt][it][1] * inv);
      uint32_t hi = pk2bf(o[mt][it][2] * inv, o[mt][it][3] * inv);
      *(uint2*)(Ob + trow + mt * 16 + q * 4) = make_uint2(lo, hi);
    }
  }
}

extern "C" void kernel_launch(void* const* d_in, const int* in_sizes, int n_in,
                              void* d_out, int out_size, void* d_ws, size_t ws_size,
                              hipStream_t stream) {
  (void)in_sizes; (void)n_in; (void)out_size; (void)ws_size;
  const float* query = (const float*)d_in[0];
  const float* key_  = (const float*)d_in[1];
  const float* value = (const float*)d_in[2];
  const float* Wq = (const float*)d_in[3]; const float* bq = (const float*)d_in[4];
  const float* Wk = (const float*)d_in[5]; const float* bk = (const float*)d_in[6];
  const float* Wv = (const float*)d_in[7]; const float* bv = (const float*)d_in[8];
  const float* Wo = (const float*)d_in[9]; const float* bo = (const float*)d_in[10];

  const size_t SZ = (size_t)8192 * 1024;  // elements per (B*T, D) bf16 tensor
  uint16_t* buf0 = (uint16_t*)d_ws;       // qb
  uint16_t* buf1 = buf0 + SZ;             // kb
  uint16_t* buf2 = buf1 + SZ;             // vb -> later attn-out
  uint16_t* buf3 = buf2 + SZ;             // Qp
  uint16_t* wts  = buf3 + SZ;             // 4 x 1M bf16 transposed weights
  uint16_t* Wtq = wts;
  uint16_t* Wtk = wts + 1048576;
  uint16_t* Wtv = wts + 2097152;
  uint16_t* Wto = wts + 3145728;
  uint16_t* Kp  = wts + 4194304;
  uint16_t* Vt  = Kp + SZ;

  const float Cs = 0.125f * LOG2E;  // folded into Q projection

  convert_inputs<<<dim3(4096, 3), 256, 0, stream>>>(query, key_, value, buf0, buf1, buf2);
  transpose_weights<<<dim3(32, 32, 4), 256, 0, stream>>>(Wq, Wk, Wv, Wo, wts);
  gemm_qkv<<<dim3(8, 64, 3), 256, 0, stream>>>(buf0, buf1, buf2, Wtq, Wtk, Wtv,
                                               bq, bk, bv, buf3, Kp, Vt, Cs);
  attn<<<dim3(8, 64), 256, 0, stream>>>(buf3, Kp, Vt, buf2);
  gemm_out<<<dim3(8, 64), 256, 0, stream>>>(buf2, Wto, bo, (float*)d_out);
}